// Round 14
// baseline (1039.504 us; speedup 1.0000x reference)
//
#include <hip/hip_runtime.h>

// LinearRNN: ys[t] = A^(t+1) @ y_init[0], t = 0..8191, D = 2048.
// Row-vector convention: T = A^T, rows[t] = y1 * T^(t+1).
// fp16 2-limb split: x = h + m*2^-12; 3 limb products (hh -> acc0, mh+hm ->
// acc1), combined as acc0 + acc1*2^-12.
// R14: block 64x64, 256 thr, 4 waves 2Mx2N, wave tile 32x32, BK=32.
// Staged/step = 16KB (A 8KB + B 8KB); 2-buffer ring = 32KB LDS -> 5 blocks/CU
// capacity; grid 1024 (32x32 panels) -> 4 blocks/CU RESIDENT (16 waves/CU).
// R13's null: capacity 3 with a 512-grid still gave 2/CU. This round raises
// the grid, not just the cap. One barrier/step (same proof as R13). Compact
// per-XCD tiling: XCD owns 16m x 8n panels. Amplification A x2 / B x2.
// Schedule: 11 fused squaring+doubling launches + 3 chain GEMMs of M=2048.

#define D 2048
#define STEPS 8192
#define KB2 2048

typedef __attribute__((ext_vector_type(8))) short short8;
typedef __attribute__((ext_vector_type(8))) _Float16 half8;
typedef __attribute__((ext_vector_type(4))) float f32x4;
typedef __attribute__((ext_vector_type(4))) unsigned short ushort4v;
typedef __attribute__((ext_vector_type(8))) unsigned short ushort8v;
typedef unsigned short ushort;

// fp16 2-limb split: x ~= h + m*2^-12  (m pre-scaled by 4096 to stay normal)
__device__ __forceinline__ void split2(float x, ushort& h, ushort& m) {
    const _Float16 hh = (_Float16)x;
    const float r = x - (float)hh;
    const _Float16 mm = (_Float16)(r * 4096.0f);
    h = __builtin_bit_cast(ushort, hh);
    m = __builtin_bit_cast(ushort, mm);
}

// Packed-layout element addresses (in elements). Fragment = 16 rows x 32 k = 1KB.
// PA: [rb=r>>7][kt=k>>5] block of 8192 elems: [L][rf=(r>>4)&7][lane][e]
__device__ __forceinline__ size_t pa_addr(int r, int k, int L) {
    return (size_t)((r >> 7) * 64 + (k >> 5)) * 8192
         + (size_t)((L * 8 + ((r >> 4) & 7)) * 512
                    + ((r & 15) + 16 * ((k >> 3) & 3)) * 8 + (k & 7));
}
// PB: [cb=c>>6][kt=k>>5] block of 4096 elems: [L][cf=(c>>4)&3][lane][e]
__device__ __forceinline__ size_t pb_addr(int c, int k, int L) {
    return (size_t)((c >> 6) * 64 + (k >> 5)) * 4096
         + (size_t)((L * 4 + ((c >> 4) & 3)) * 512
                    + ((c & 15) + 16 * ((k >> 3) & 3)) * 8 + (k & 7));
}

__device__ __forceinline__ ushort8v mk8(const ushort* p) {
    ushort8v v = {p[0], p[1], p[2], p[3], p[4], p[5], p[6], p[7]};
    return v;
}

__device__ __forceinline__ void gload16(const void* g, void* l) {
    __builtin_amdgcn_global_load_lds(
        (const __attribute__((address_space(1))) unsigned int*)g,
        (__attribute__((address_space(3))) unsigned int*)l, 16, 0, 0);
}

__device__ __forceinline__ void vmwait0() { asm volatile("s_waitcnt vmcnt(0)" ::: "memory"); }
__device__ __forceinline__ void barfence() {
    __builtin_amdgcn_sched_barrier(0);
    __builtin_amdgcn_s_barrier();
    __builtin_amdgcn_sched_barrier(0);
}

// ---------------- prep: A -> PA-packed of T and PB-packed of T ----------------
// PA(r,k) = T[r][k] = A[k][r];  PB(c,k) = T[k][c] = A[c][k].
__global__ __launch_bounds__(256) void prep_pack(const float* __restrict__ A,
                                                 ushort* PA, ushort* PB) {
    __shared__ float tile[64][65];
    const int tid = threadIdx.x;
    const int bx = blockIdx.x * 64, by = blockIdx.y * 64;
    {
        const int rl = tid >> 2, cq = (tid & 3) * 16;
        const float* src = &A[(size_t)(by + rl) * D + bx + cq];
#pragma unroll
        for (int i = 0; i < 4; ++i) {
            float4 v = *reinterpret_cast<const float4*>(src + i * 4);
            tile[rl][cq + i * 4 + 0] = v.x;
            tile[rl][cq + i * 4 + 1] = v.y;
            tile[rl][cq + i * 4 + 2] = v.z;
            tile[rl][cq + i * 4 + 3] = v.w;
        }
    }
    __syncthreads();
    const int off = tid & 63, kc = tid >> 6;
    ushort hb[16], mb[16];
    // PA: r = bx+off, k = by+kc*16+kk, val = A[k][r]
#pragma unroll
    for (int kk = 0; kk < 16; ++kk)
        split2(tile[kc * 16 + kk][off], hb[kk], mb[kk]);
#pragma unroll
    for (int g = 0; g < 2; ++g) {
        const size_t a0 = pa_addr(bx + off, by + kc * 16 + g * 8, 0);
        *(ushort8v*)&PA[a0]        = mk8(hb + g * 8);
        *(ushort8v*)&PA[a0 + 4096] = mk8(mb + g * 8);
    }
    // PB: c = by+off, k = bx+kc*16+kk, val = A[c][k]
#pragma unroll
    for (int kk = 0; kk < 16; ++kk)
        split2(tile[off][kc * 16 + kk], hb[kk], mb[kk]);
#pragma unroll
    for (int g = 0; g < 2; ++g) {
        const size_t b0 = pb_addr(by + off, bx + kc * 16 + g * 8, 0);
        *(ushort8v*)&PB[b0]        = mk8(hb + g * 8);
        *(ushort8v*)&PB[b0 + 2048] = mk8(mb + g * 8);
    }
}

// ---------------- seed: rows[0] = y1 * T via fp32 matvec over PB-packed ----------------
__global__ __launch_bounds__(256) void seed_mv(const float* __restrict__ y,
                                               const ushort* __restrict__ PB,
                                               float* __restrict__ outF,
                                               ushort* __restrict__ PAout) {
    __shared__ float ys[D];
    const int tid = threadIdx.x;
    for (int i = tid; i < D; i += 256) ys[i] = y[i];
    __syncthreads();
    const int c = blockIdx.x * 64 + (tid >> 2);
    const int ks = tid & 3;
    const ushort* pb = PB + (size_t)(c >> 6) * (64 * 4096);
    const int lofs = (((c >> 4) & 3) * 512 + ((c & 15) + 16 * ks) * 8);
    float sum = 0.f;
    for (int kt = 0; kt < 64; ++kt) {
        const size_t base = (size_t)kt * 4096 + lofs;
        ushort8v h8 = *(const ushort8v*)&pb[base];
        ushort8v m8 = *(const ushort8v*)&pb[base + 2048];
#pragma unroll
        for (int e = 0; e < 8; ++e) {
            const float hv = (float)__builtin_bit_cast(_Float16, (ushort)h8[e]);
            const float mv = (float)__builtin_bit_cast(_Float16, (ushort)m8[e]);
            sum += (hv + mv * (1.0f / 4096.0f)) * ys[kt * 32 + ks * 8 + e];
        }
    }
    sum += __shfl_down(sum, 2);
    sum += __shfl_down(sum, 1);
    if (ks == 0) {
        outF[c] = sum;
        ushort h, m;
        split2(sum, h, m);
        const size_t a0 = pa_addr(0, c, 0);
        PAout[a0] = h;
        PAout[a0 + 4096] = m;
    }
}

// ---------------- split-fp16 MFMA GEMM (+ optional fused doubling rows) ----------------
// Block 64x64, 256 thr, 4 waves 2Mx2N, wave tile 32x32, BK=32, 64 k-steps.
// LDS: 2 buffers x 16KB = 32KB -> grid 1024 gives 4 blocks/CU resident.
// Staging: 16 1KB wave-regions per step; waves 0-1 stage A (two 4KB limb
// pieces at rf0=(m0>>4)&7), waves 2-3 stage B (contiguous 8KB).
// blockIdx.y < 32: compact per-XCD tiling (XCD = orig&7 owns 16m x 8n panels).
// blockIdx.y >= 32 (fused launches): doubling rows, generic swizzle.
__global__ __launch_bounds__(256, 4)
void gemm3(const ushort* __restrict__ Xsq, const ushort* __restrict__ Xdbl,
           const ushort* __restrict__ W,
           float* __restrict__ outF, ushort* __restrict__ PAout, int ro,
           ushort* __restrict__ PNo, ushort* __restrict__ PBo,
           int M, int wantPN) {
    __shared__ __align__(16) char smem[2 * 16384];
    char* ldsc = (char*)smem;
    const int tid = threadIdx.x;
    const int w = tid >> 6, lane = tid & 63;

    const bool dbl = (blockIdx.y >= 32);
    int n0, m0;
    if (!dbl) {
        const int orig = blockIdx.y * 32 + blockIdx.x;   // 0..1023
        const int x = orig & 7;                          // XCD (round-robin)
        const int local = orig >> 3;                     // 0..127
        const int mi = (x & 1) * 16 + (local >> 3);      // 0..31
        const int ni = (x >> 1) * 8 + (local & 7);       // 0..31
        m0 = mi * 64;
        n0 = ni * 64;
    } else {
        const int nwg = 32 * ((int)gridDim.y - 32);
        int id = (blockIdx.y - 32) * 32 + blockIdx.x;
        const int cpx = nwg >> 3; id = (id & 7) * cpx + (id >> 3);
        n0 = (id & 31) * 64;
        m0 = (id / 32) * 64;
    }
    const ushort* X = dbl ? Xdbl : Xsq;
    const bool sq = (!dbl) && (PBo != nullptr);

    const int wm = w >> 1, wn = w & 1;   // 2M x 2N wave grid

    // staging: wave w stages regions w*4+g (g=0..3); regions 0-7 = A, 8-15 = B.
    // A region r: L = r>>2, rfLocal = r&3, src = PAblk + (L*8+rf0+rfLocal)*1KB.
    // B region r: src = PBblk + (r-8)*1KB. LDS dest = region*1KB (wave-uniform).
    const int rf0 = (m0 >> 4) & 7;                       // 0 or 4
    const char* gAblk = (const char*)X + (size_t)(m0 >> 7) * (64 * 16384);
    const char* gBblk = (const char*)W + (size_t)(n0 >> 6) * (64 * 8192);
    const char* gsrc[4];
    int ldst[4];
#pragma unroll
    for (int g = 0; g < 4; ++g) {
        const int r = w * 4 + g;
        ldst[g] = r * 1024;
        if (r < 8)
            gsrc[g] = gAblk + ((r >> 2) * 8 + rf0 + (r & 3)) * 1024 + lane * 16;
        else
            gsrc[g] = gBblk + (r - 8) * 1024 + lane * 16;
    }
    const bool isA = (w < 2);

    auto stage = [&](int off, int kt) {
        const size_t ks = (size_t)kt * (isA ? 16384 : 8192);
#pragma unroll
        for (int g = 0; g < 4; ++g)
            gload16(gsrc[g] + ks, ldsc + off + ldst[g]);
    };

    // fragment ds_read byte offsets: frag_base + lane*16 (conflict-free)
    int aoff[2][2], boff[2][2];
#pragma unroll
    for (int L = 0; L < 2; ++L) {
#pragma unroll
        for (int q = 0; q < 2; ++q)
            aoff[L][q] = (L * 4 + wm * 2 + q) * 1024 + lane * 16;
#pragma unroll
        for (int nr = 0; nr < 2; ++nr)
            boff[L][nr] = 8192 + (L * 4 + wn * 2 + nr) * 1024 + lane * 16;
    }

    f32x4 acc0[2][2] = {}, acc1[2][2] = {};

    auto compute = [&](int off) {
        // h-limb fragments first: the hh MFMA cluster can start after 4 reads
        short8 a0f[2], b0f[2], a1f[2], b1f[2];
#pragma unroll
        for (int q = 0; q < 2; ++q) a0f[q] = *(const short8*)(ldsc + off + aoff[0][q]);
#pragma unroll
        for (int nr = 0; nr < 2; ++nr) b0f[nr] = *(const short8*)(ldsc + off + boff[0][nr]);
#pragma unroll
        for (int q = 0; q < 2; ++q) a1f[q] = *(const short8*)(ldsc + off + aoff[1][q]);
#pragma unroll
        for (int nr = 0; nr < 2; ++nr) b1f[nr] = *(const short8*)(ldsc + off + boff[1][nr]);
        __builtin_amdgcn_s_setprio(1);
#define H8(x) __builtin_bit_cast(half8, x)
#define MM(d, x, y) d = __builtin_amdgcn_mfma_f32_16x16x32_f16(H8(x), H8(y), d, 0, 0, 0)
#pragma unroll
        for (int i = 0; i < 2; ++i)
#pragma unroll
            for (int j = 0; j < 2; ++j) MM(acc0[i][j], a0f[i], b0f[j]);   // h*h
#pragma unroll
        for (int i = 0; i < 2; ++i)
#pragma unroll
            for (int j = 0; j < 2; ++j) MM(acc1[i][j], a1f[i], b0f[j]);   // m*h
#pragma unroll
        for (int i = 0; i < 2; ++i)
#pragma unroll
            for (int j = 0; j < 2; ++j) MM(acc1[i][j], a0f[i], b1f[j]);   // h*m
#undef MM
#undef H8
        __builtin_amdgcn_s_setprio(0);
    };

    // ---- K-loop: 2-buffer ring, ONE barrier per step, depth-1 prefetch ----
    // round t: vmwait0 (my stage(t) loads done); barrier (=> all stage(t) done
    // AND all compute(t-1) -- last readers of buf[(t+1)&1] -- retired);
    // stage(t+1) -> buf[(t+1)&1]; compute(t) <- buf[t&1].
    stage(0, 0);
#define STEP(T, CBUF, SBUF)   \
    vmwait0();                \
    barfence();               \
    stage(SBUF, (T) + 1);     \
    compute(CBUF);
    for (int tb = 0; tb < 62; tb += 2) {
        STEP(tb + 0, 0,     16384)
        STEP(tb + 1, 16384, 0)
    }
    STEP(62, 0, 16384)        // stages kt=63
#undef STEP
    vmwait0();
    barfence();
    compute(16384);           // t = 63

    // epilogue: C/D layout col = lane&15, row = (lane>>4)*4 + j (verified)
    const int row0 = m0 + wm * 32 + (lane >> 4) * 4;
    const int col0 = n0 + wn * 32 + (lane & 15);
#pragma unroll
    for (int mr = 0; mr < 2; ++mr) {
#pragma unroll
        for (int nr = 0; nr < 2; ++nr) {
            const int c = col0 + nr * 16;
            const int rb0 = row0 + mr * 16;
            f32x4 vv;
#pragma unroll
            for (int j = 0; j < 4; ++j)
                vv[j] = acc0[mr][nr][j] + acc1[mr][nr][j] * (1.0f / 4096.0f);
            if (sq) {
                ushort hs[4], ms[4];
#pragma unroll
                for (int j = 0; j < 4; ++j) {
                    split2(vv[j], hs[j], ms[j]);
                    if (wantPN) {
                        const size_t a0 = pa_addr(rb0 + j, c, 0);
                        PNo[a0] = hs[j]; PNo[a0 + 4096] = ms[j];
                    }
                }
                const size_t b0 = pb_addr(c, rb0, 0);
                ushort4v hv = {hs[0], hs[1], hs[2], hs[3]};
                ushort4v mv = {ms[0], ms[1], ms[2], ms[3]};
                *(ushort4v*)&PBo[b0]        = hv;
                *(ushort4v*)&PBo[b0 + 2048] = mv;
            } else {
#pragma unroll
                for (int j = 0; j < 4; ++j) {
                    const int r = rb0 + j;
                    if (r < M) {
                        outF[(size_t)r * D + c] = vv[j];
                        if (PAout) {
                            ushort h, m;
                            split2(vv[j], h, m);
                            const size_t a0 = pa_addr(r + ro, c, 0);
                            PAout[a0] = h; PAout[a0 + 4096] = m;
                        }
                    }
                }
            }
        }
    }
}

// ================= fp32 fallback (round-1, known-good) =================
__global__ void transpose_k(const float* __restrict__ A, float* __restrict__ T) {
    __shared__ float tile[32][33];
    const int bx = blockIdx.x * 32, by = blockIdx.y * 32;
    const int tx = threadIdx.x, ty = threadIdx.y;
#pragma unroll
    for (int i = 0; i < 32; i += 8)
        tile[ty + i][tx] = A[(size_t)(by + ty + i) * D + bx + tx];
    __syncthreads();
#pragma unroll
    for (int i = 0; i < 32; i += 8)
        T[(size_t)(bx + ty + i) * D + by + tx] = tile[tx][ty + i];
}

__global__ __launch_bounds__(256) void gemm_rows(const float* __restrict__ X,
                                                 const float* __restrict__ W,
                                                 float* __restrict__ C, int M) {
    __shared__ float As[16][34];
    __shared__ float Bs[16][68];
    const int n0 = blockIdx.x * 64;
    const int m0 = blockIdx.y * 32;
    const int tid = threadIdx.x;
    const int ty = tid >> 4, tx = tid & 15;
    const int rs = tid >> 3;
    const int ks = (tid & 7) * 2;
    const int rclamp = min(m0 + rs, M - 1);
    const int kb = tid >> 4;
    const int nb = (tid & 15) * 4;
    float acc[2][4] = {{0.f, 0.f, 0.f, 0.f}, {0.f, 0.f, 0.f, 0.f}};
    for (int k0 = 0; k0 < D; k0 += 16) {
        float2 xa = *reinterpret_cast<const float2*>(&X[(size_t)rclamp * D + k0 + ks]);
        float4 wb = *reinterpret_cast<const float4*>(&W[(size_t)(k0 + kb) * D + n0 + nb]);
        As[ks][rs] = xa.x;
        As[ks + 1][rs] = xa.y;
        *reinterpret_cast<float4*>(&Bs[kb][nb]) = wb;
        __syncthreads();
#pragma unroll
        for (int kk = 0; kk < 16; ++kk) {
            float2 a = *reinterpret_cast<const float2*>(&As[kk][ty * 2]);
            float4 b = *reinterpret_cast<const float4*>(&Bs[kk][tx * 4]);
            acc[0][0] += a.x * b.x; acc[0][1] += a.x * b.y;
            acc[0][2] += a.x * b.z; acc[0][3] += a.x * b.w;
            acc[1][0] += a.y * b.x; acc[1][1] += a.y * b.y;
            acc[1][2] += a.y * b.z; acc[1][3] += a.y * b.w;
        }
        __syncthreads();
    }
#pragma unroll
    for (int i = 0; i < 2; ++i) {
        const int m = m0 + ty * 2 + i;
        if (m < M) {
            float4 v = make_float4(acc[i][0], acc[i][1], acc[i][2], acc[i][3]);
            *reinterpret_cast<float4*>(&C[(size_t)m * D + n0 + tx * 4]) = v;
        }
    }
}

__global__ __launch_bounds__(256, 2) void gemm_big(const float* __restrict__ X,
                                                   const float* __restrict__ W,
                                                   float* __restrict__ C) {
    __shared__ float As[16][132];
    __shared__ float Bs[16][68];
    const int n0 = blockIdx.x * 64;
    const int m0 = blockIdx.y * 128;
    const int tid = threadIdx.x;
    const int ty = tid >> 4, tx = tid & 15;
    const int ra = tid >> 2;
    const int ka = (tid & 3) * 4;
    const int kb = tid >> 4;
    const int nb = (tid & 15) * 4;
    float acc[8][4];
#pragma unroll
    for (int i = 0; i < 8; ++i) { acc[i][0] = 0.f; acc[i][1] = 0.f; acc[i][2] = 0.f; acc[i][3] = 0.f; }
    for (int k0 = 0; k0 < D; k0 += 16) {
        float4 a0 = *reinterpret_cast<const float4*>(&X[(size_t)(m0 + ra) * D + k0 + ka]);
        float4 a1 = *reinterpret_cast<const float4*>(&X[(size_t)(m0 + ra + 64) * D + k0 + ka]);
        float4 wb = *reinterpret_cast<const float4*>(&W[(size_t)(k0 + kb) * D + n0 + nb]);
        As[ka][ra] = a0.x; As[ka + 1][ra] = a0.y; As[ka + 2][ra] = a0.z; As[ka + 3][ra] = a0.w;
        As[ka][ra + 64] = a1.x; As[ka + 1][ra + 64] = a1.y;
        As[ka + 2][ra + 64] = a1.z; As[ka + 3][ra + 64] = a1.w;
        *reinterpret_cast<float4*>(&Bs[kb][nb]) = wb;
        __syncthreads();
#pragma unroll
        for (int kk = 0; kk < 16; ++kk) {
            float4 a04 = *reinterpret_cast<const float4*>(&As[kk][ty * 8]);
            float4 a14 = *reinterpret_cast<const float4*>(&As[kk][ty * 8 + 4]);
            float4 b4  = *reinterpret_cast<const float4*>(&Bs[kk][tx * 4]);
            const float av[8] = {a04.x, a04.y, a04.z, a04.w, a14.x, a14.y, a14.z, a14.w};
            const float bv[4] = {b4.x, b4.y, b4.z, b4.w};
#pragma unroll
            for (int i = 0; i < 8; ++i)
#pragma unroll
                for (int j = 0; j < 4; ++j)
                    acc[i][j] += av[i] * bv[j];
        }
        __syncthreads();
    }
#pragma unroll
    for (int i = 0; i < 8; ++i) {
        float4 v = make_float4(acc[i][0], acc[i][1], acc[i][2], acc[i][3]);
        *reinterpret_cast<float4*>(&C[(size_t)(m0 + ty * 8 + i) * D + n0 + tx * 4]) = v;
    }
}

__global__ void matvec_rowdot(const float* __restrict__ A, const float* __restrict__ y,
                              float* __restrict__ out) {
    const int wave = threadIdx.x >> 6, lane = threadIdx.x & 63;
    const int row = blockIdx.x * 4 + wave;
    const float* ar = A + (size_t)row * D;
    float s = 0.f;
#pragma unroll 8
    for (int k = lane; k < D; k += 64) s += ar[k] * y[k];
#pragma unroll
    for (int off = 32; off; off >>= 1) s += __shfl_down(s, off);
    if (lane == 0) out[row] = s;
}

// ================= host =================
extern "C" void kernel_launch(void* const* d_in, const int* in_sizes, int n_in,
                              void* d_out, int out_size, void* d_ws, size_t ws_size,
                              hipStream_t stream) {
    const float* A = (const float*)d_in[0];
    const float* y_init = (const float*)d_in[1];
    float* out = (float*)d_out;

    const size_t packFull = (size_t)16 * 64 * 16384;   // 16 MiB per packed matrix
    const size_t need = 5 * packFull;                  // 80 MiB

    if (ws_size >= need) {
        char* c = (char*)d_ws;
        ushort* PT[2]; ushort* PN[2]; ushort* rg[2];
        PT[0] = (ushort*)c; c += packFull;
        PT[1] = (ushort*)c; c += packFull;
        PN[0] = (ushort*)c; c += packFull;
        PN[1] = (ushort*)c; c += packFull;
        rg[0] = (ushort*)c; c += packFull;
        rg[1] = PN[0];        // last read by squaring i=10; first write chain j=1

        prep_pack<<<dim3(32, 32), 256, 0, stream>>>(A, PN[0], PT[0]);

        // seed: rows[0] = y1 * T  (fp32 matvec over PB-packed T)
        seed_mv<<<32, 256, 0, stream>>>(y_init, PT[0], out, rg[0]);

        // fused squaring + doubling: i = 0..10
        int cur = 0;
        for (int i = 0; i < 11; ++i) {
            const int m = 1 << i;
            const int nd = (m + 63) / 64;
            gemm3<<<dim3(32, 32 + nd), 256, 0, stream>>>(
                PN[cur], rg[0], PT[cur],
                out + (size_t)m * D, rg[0], m,
                PN[cur ^ 1], PT[cur ^ 1],
                m, (i < 10) ? 1 : 0);
            cur ^= 1;
        }
        // cur == 1: PT[1] = T^2048

        // chain: rows[j*2048..(j+1)*2048) = rows[(j-1)*2048..) * T^2048
        for (int j = 1; j < STEPS / KB2; ++j) {
            gemm3<<<dim3(32, 32), 256, 0, stream>>>(
                rg[(j - 1) & 1], nullptr, PT[cur],
                out + (size_t)j * KB2 * D,
                (j < STEPS / KB2 - 1) ? rg[j & 1] : nullptr, 0,
                nullptr, nullptr, 2048, 0);
        }
    } else if (ws_size >= 2 * (size_t)D * D * sizeof(float)) {
        // fp32 fallback (round-1 path, known-good)
        float* Pa = (float*)d_ws;
        float* Pb = Pa + (size_t)D * D;
        transpose_k<<<dim3(D / 32, D / 32), dim3(32, 8), 0, stream>>>(A, Pa);
        gemm_rows<<<dim3(D / 64, 1), 256, 0, stream>>>(y_init, Pa, out, 1);
        float* cur = Pa;
        float* nxt = Pb;
        for (int m = 1; m < 256; m <<= 1) {
            gemm_rows<<<dim3(D / 64, (m + 31) / 32), 256, 0, stream>>>(
                out, cur, out + (size_t)m * D, m);
            gemm_big<<<dim3(D / 64, D / 128), 256, 0, stream>>>(cur, cur, nxt);
            float* t = cur; cur = nxt; nxt = t;
        }
        for (int j = 1; j < STEPS / 256; ++j) {
            gemm_rows<<<dim3(D / 64, 256 / 32), 256, 0, stream>>>(
                out + (size_t)(j - 1) * 256 * D, cur, out + (size_t)j * 256 * D, 256);
        }
    } else {
        matvec_rowdot<<<D / 4, 256, 0, stream>>>(A, y_init, out);
        for (int t = 1; t < STEPS; ++t)
            matvec_rowdot<<<D / 4, 256, 0, stream>>>(A, out + (size_t)(t - 1) * D,
                                                     out + (size_t)t * D);
    }
}

// Round 15
// 909.871 us; speedup vs baseline: 1.1425x; 1.1425x over previous
//
#include <hip/hip_runtime.h>

// LinearRNN: ys[t] = A^(t+1) @ y_init[0], t = 0..8191, D = 2048.
// Row-vector convention: T = A^T, rows[t] = y1 * T^(t+1).
// fp16 2-limb split: x = h + m*2^-12; 3 limb products (hh -> acc0, mh+hm ->
// acc1), combined as acc0 + acc1*2^-12.
// Engine (R12 = measured optimum, reverted from R13/R14 experiments):
// block 128x64, 512 thr, 8 waves 4Mx2N, wave tile 32x32, BK=32; A+B staged in
// LDS (3 x 24KB ring -> 2 blocks/CU); ONE barrier per k-step; counted
// vmwait(3) (never 0 in loop); fragment-packed operands; ds_read_b128
// frag_base+lane*16 (0 bank conflicts); compact per-XCD tiling (each XCD's 64
// concurrent blocks cover an 8m x 8n panel tile); seed via fp32 matvec.
// Schedule: 11 fused squaring+doubling launches + 3 chain GEMMs of M=2048.

#define D 2048
#define STEPS 8192
#define KB2 2048

typedef __attribute__((ext_vector_type(8))) short short8;
typedef __attribute__((ext_vector_type(8))) _Float16 half8;
typedef __attribute__((ext_vector_type(4))) float f32x4;
typedef __attribute__((ext_vector_type(4))) unsigned short ushort4v;
typedef __attribute__((ext_vector_type(8))) unsigned short ushort8v;
typedef unsigned short ushort;

// fp16 2-limb split: x ~= h + m*2^-12  (m pre-scaled by 4096 to stay normal)
__device__ __forceinline__ void split2(float x, ushort& h, ushort& m) {
    const _Float16 hh = (_Float16)x;
    const float r = x - (float)hh;
    const _Float16 mm = (_Float16)(r * 4096.0f);
    h = __builtin_bit_cast(ushort, hh);
    m = __builtin_bit_cast(ushort, mm);
}

// Packed-layout element addresses (in elements). Fragment = 16 rows x 32 k = 1KB.
// PA: [rb=r>>7][kt=k>>5] block of 8192 elems: [L][rf=(r>>4)&7][lane][e]
__device__ __forceinline__ size_t pa_addr(int r, int k, int L) {
    return (size_t)((r >> 7) * 64 + (k >> 5)) * 8192
         + (size_t)((L * 8 + ((r >> 4) & 7)) * 512
                    + ((r & 15) + 16 * ((k >> 3) & 3)) * 8 + (k & 7));
}
// PB: [cb=c>>6][kt=k>>5] block of 4096 elems: [L][cf=(c>>4)&3][lane][e]
__device__ __forceinline__ size_t pb_addr(int c, int k, int L) {
    return (size_t)((c >> 6) * 64 + (k >> 5)) * 4096
         + (size_t)((L * 4 + ((c >> 4) & 3)) * 512
                    + ((c & 15) + 16 * ((k >> 3) & 3)) * 8 + (k & 7));
}

__device__ __forceinline__ ushort8v mk8(const ushort* p) {
    ushort8v v = {p[0], p[1], p[2], p[3], p[4], p[5], p[6], p[7]};
    return v;
}

__device__ __forceinline__ void gload16(const void* g, void* l) {
    __builtin_amdgcn_global_load_lds(
        (const __attribute__((address_space(1))) unsigned int*)g,
        (__attribute__((address_space(3))) unsigned int*)l, 16, 0, 0);
}

template<int N> __device__ __forceinline__ void vmwait();
template<> __device__ __forceinline__ void vmwait<0>() { asm volatile("s_waitcnt vmcnt(0)" ::: "memory"); }
template<> __device__ __forceinline__ void vmwait<3>() { asm volatile("s_waitcnt vmcnt(3)" ::: "memory"); }
__device__ __forceinline__ void barfence() {
    __builtin_amdgcn_sched_barrier(0);
    __builtin_amdgcn_s_barrier();
    __builtin_amdgcn_sched_barrier(0);
}

// ---------------- prep: A -> PA-packed of T and PB-packed of T ----------------
// PA(r,k) = T[r][k] = A[k][r];  PB(c,k) = T[k][c] = A[c][k].
__global__ __launch_bounds__(256) void prep_pack(const float* __restrict__ A,
                                                 ushort* PA, ushort* PB) {
    __shared__ float tile[64][65];
    const int tid = threadIdx.x;
    const int bx = blockIdx.x * 64, by = blockIdx.y * 64;
    {
        const int rl = tid >> 2, cq = (tid & 3) * 16;
        const float* src = &A[(size_t)(by + rl) * D + bx + cq];
#pragma unroll
        for (int i = 0; i < 4; ++i) {
            float4 v = *reinterpret_cast<const float4*>(src + i * 4);
            tile[rl][cq + i * 4 + 0] = v.x;
            tile[rl][cq + i * 4 + 1] = v.y;
            tile[rl][cq + i * 4 + 2] = v.z;
            tile[rl][cq + i * 4 + 3] = v.w;
        }
    }
    __syncthreads();
    const int off = tid & 63, kc = tid >> 6;
    ushort hb[16], mb[16];
    // PA: r = bx+off, k = by+kc*16+kk, val = A[k][r]
#pragma unroll
    for (int kk = 0; kk < 16; ++kk)
        split2(tile[kc * 16 + kk][off], hb[kk], mb[kk]);
#pragma unroll
    for (int g = 0; g < 2; ++g) {
        const size_t a0 = pa_addr(bx + off, by + kc * 16 + g * 8, 0);
        *(ushort8v*)&PA[a0]        = mk8(hb + g * 8);
        *(ushort8v*)&PA[a0 + 4096] = mk8(mb + g * 8);
    }
    // PB: c = by+off, k = bx+kc*16+kk, val = A[c][k]
#pragma unroll
    for (int kk = 0; kk < 16; ++kk)
        split2(tile[off][kc * 16 + kk], hb[kk], mb[kk]);
#pragma unroll
    for (int g = 0; g < 2; ++g) {
        const size_t b0 = pb_addr(by + off, bx + kc * 16 + g * 8, 0);
        *(ushort8v*)&PB[b0]        = mk8(hb + g * 8);
        *(ushort8v*)&PB[b0 + 2048] = mk8(mb + g * 8);
    }
}

// ---------------- seed: rows[0] = y1 * T via fp32 matvec over PB-packed ----------------
__global__ __launch_bounds__(256) void seed_mv(const float* __restrict__ y,
                                               const ushort* __restrict__ PB,
                                               float* __restrict__ outF,
                                               ushort* __restrict__ PAout) {
    __shared__ float ys[D];
    const int tid = threadIdx.x;
    for (int i = tid; i < D; i += 256) ys[i] = y[i];
    __syncthreads();
    const int c = blockIdx.x * 64 + (tid >> 2);
    const int ks = tid & 3;
    const ushort* pb = PB + (size_t)(c >> 6) * (64 * 4096);
    const int lofs = (((c >> 4) & 3) * 512 + ((c & 15) + 16 * ks) * 8);
    float sum = 0.f;
    for (int kt = 0; kt < 64; ++kt) {
        const size_t base = (size_t)kt * 4096 + lofs;
        ushort8v h8 = *(const ushort8v*)&pb[base];
        ushort8v m8 = *(const ushort8v*)&pb[base + 2048];
#pragma unroll
        for (int e = 0; e < 8; ++e) {
            const float hv = (float)__builtin_bit_cast(_Float16, (ushort)h8[e]);
            const float mv = (float)__builtin_bit_cast(_Float16, (ushort)m8[e]);
            sum += (hv + mv * (1.0f / 4096.0f)) * ys[kt * 32 + ks * 8 + e];
        }
    }
    sum += __shfl_down(sum, 2);
    sum += __shfl_down(sum, 1);
    if (ks == 0) {
        outF[c] = sum;
        ushort h, m;
        split2(sum, h, m);
        const size_t a0 = pa_addr(0, c, 0);
        PAout[a0] = h;
        PAout[a0 + 4096] = m;
    }
}

// ---------------- split-fp16 MFMA GEMM (+ optional fused doubling rows) ----------------
// Block 128x64, 512 thr, 8 waves 4Mx2N, wave tile 32x32, BK=32, 64 k-steps.
// LDS: 3 buffers x 24KB (A 16KB + B 8KB) = 72KB -> 2 blocks/CU.
// blockIdx.y < 16: compact per-XCD tiling (XCD = orig&7 owns an 8m x 8n tile).
// blockIdx.y >= 16 (fused launches): doubling rows, generic swizzle.
__global__ __launch_bounds__(512, 4)
void gemm3(const ushort* __restrict__ Xsq, const ushort* __restrict__ Xdbl,
           const ushort* __restrict__ W,
           float* __restrict__ outF, ushort* __restrict__ PAout, int ro,
           ushort* __restrict__ PNo, ushort* __restrict__ PBo,
           int M, int wantPN) {
    __shared__ __align__(16) char smem[3 * 24576];
    char* ldsc = (char*)smem;
    const int tid = threadIdx.x;
    const int w = tid >> 6, lane = tid & 63;

    const bool dbl = (blockIdx.y >= 16);
    int n0, m0;
    if (!dbl) {
        const int orig = blockIdx.y * 32 + blockIdx.x;   // 0..511
        const int x = orig & 7;                          // XCD (round-robin)
        const int local = orig >> 3;                     // 0..63
        const int mi = (x & 1) * 8 + (local >> 3);       // 0..15
        const int ni = (x >> 1) * 8 + (local & 7);       // 0..31
        m0 = mi * 128;
        n0 = ni * 64;
    } else {
        const int nwg = 32 * ((int)gridDim.y - 16);
        int id = (blockIdx.y - 16) * 32 + blockIdx.x;
        const int cpx = nwg >> 3; id = (id & 7) * cpx + (id >> 3);
        n0 = (id & 31) * 64;
        m0 = (id / 32) * 128;
    }
    const ushort* X = dbl ? Xdbl : Xsq;
    const bool sq = (!dbl) && (PBo != nullptr);

    const int wm = w >> 1, wn = w & 1;   // 4M x 2N wave grid

    // staging: per (rb,kt) A-block = 16384 B, B-block = 8192 B, both linear
    const char* gA = (const char*)X + (size_t)(m0 >> 7) * (64 * 16384) + (size_t)tid * 16;
    const char* gB = (const char*)W + (size_t)(n0 >> 6) * (64 * 8192) + (size_t)tid * 16;

    auto stage = [&](int off, int kt) {
        const char* a = gA + (size_t)kt * 16384;
        const char* b = gB + (size_t)kt * 8192;
        gload16(a, ldsc + off + w * 1024);
        gload16(a + 8192, ldsc + off + 8192 + w * 1024);
        gload16(b, ldsc + off + 16384 + w * 1024);
    };

    // fragment ds_read byte offsets: frag_base + lane*16 (conflict-free)
    int aoff[2][2], boff[2][2];
#pragma unroll
    for (int L = 0; L < 2; ++L) {
#pragma unroll
        for (int q = 0; q < 2; ++q)
            aoff[L][q] = (L * 8 + wm * 2 + q) * 1024 + lane * 16;
#pragma unroll
        for (int nr = 0; nr < 2; ++nr)
            boff[L][nr] = 16384 + (L * 4 + wn * 2 + nr) * 1024 + lane * 16;
    }

    f32x4 acc0[2][2] = {}, acc1[2][2] = {};

    auto compute = [&](int off) {
        // h-limb fragments first: the hh MFMA cluster can start after 4 reads
        short8 a0f[2], b0f[2], a1f[2], b1f[2];
#pragma unroll
        for (int q = 0; q < 2; ++q) a0f[q] = *(const short8*)(ldsc + off + aoff[0][q]);
#pragma unroll
        for (int nr = 0; nr < 2; ++nr) b0f[nr] = *(const short8*)(ldsc + off + boff[0][nr]);
#pragma unroll
        for (int q = 0; q < 2; ++q) a1f[q] = *(const short8*)(ldsc + off + aoff[1][q]);
#pragma unroll
        for (int nr = 0; nr < 2; ++nr) b1f[nr] = *(const short8*)(ldsc + off + boff[1][nr]);
        __builtin_amdgcn_s_setprio(1);
#define H8(x) __builtin_bit_cast(half8, x)
#define MM(d, x, y) d = __builtin_amdgcn_mfma_f32_16x16x32_f16(H8(x), H8(y), d, 0, 0, 0)
#pragma unroll
        for (int i = 0; i < 2; ++i)
#pragma unroll
            for (int j = 0; j < 2; ++j) MM(acc0[i][j], a0f[i], b0f[j]);   // h*h
#pragma unroll
        for (int i = 0; i < 2; ++i)
#pragma unroll
            for (int j = 0; j < 2; ++j) MM(acc1[i][j], a1f[i], b0f[j]);   // m*h
#pragma unroll
        for (int i = 0; i < 2; ++i)
#pragma unroll
            for (int j = 0; j < 2; ++j) MM(acc1[i][j], a0f[i], b1f[j]);   // h*m
#undef MM
#undef H8
        __builtin_amdgcn_s_setprio(0);
    };

    // ---- K-loop: 3-buffer ring, ONE barrier per step, depth-2 prefetch ----
    // iter t: vmwait<3> (stage(t) fully landed; stage(t+1)'s 3 loads stay in
    // flight across the barrier); barrier; stage(t+2) -> buf[(t+2)%3]; compute(t).
    // Single barrier is safe: buf[(t+2)%3] == buf[(t-1)%3], whose last readers
    // (compute(t-1)) retired their ds_reads before passing barrier(t).
    stage(0, 0);
    stage(24576, 1);
#define STEP(T, CBUF, SBUF)   \
    vmwait<3>();              \
    barfence();               \
    stage(SBUF, (T) + 2);     \
    compute(CBUF);
    for (int tb = 0; tb < 60; tb += 3) {
        STEP(tb + 0, 0,     49152)
        STEP(tb + 1, 24576, 0)
        STEP(tb + 2, 49152, 24576)
    }
    STEP(60, 0, 49152)        // stages kt=62
    STEP(61, 24576, 0)        // stages kt=63
#undef STEP
    vmwait<3>();
    barfence();
    compute(49152);           // t = 62
    vmwait<0>();
    barfence();
    compute(0);               // t = 63

    // epilogue: C/D layout col = lane&15, row = (lane>>4)*4 + j (verified)
    const int row0 = m0 + wm * 32 + (lane >> 4) * 4;
    const int col0 = n0 + wn * 32 + (lane & 15);
#pragma unroll
    for (int mr = 0; mr < 2; ++mr) {
#pragma unroll
        for (int nr = 0; nr < 2; ++nr) {
            const int c = col0 + nr * 16;
            const int rb0 = row0 + mr * 16;
            f32x4 vv;
#pragma unroll
            for (int j = 0; j < 4; ++j)
                vv[j] = acc0[mr][nr][j] + acc1[mr][nr][j] * (1.0f / 4096.0f);
            if (sq) {
                ushort hs[4], ms[4];
#pragma unroll
                for (int j = 0; j < 4; ++j) {
                    split2(vv[j], hs[j], ms[j]);
                    if (wantPN) {
                        const size_t a0 = pa_addr(rb0 + j, c, 0);
                        PNo[a0] = hs[j]; PNo[a0 + 4096] = ms[j];
                    }
                }
                const size_t b0 = pb_addr(c, rb0, 0);
                ushort4v hv = {hs[0], hs[1], hs[2], hs[3]};
                ushort4v mv = {ms[0], ms[1], ms[2], ms[3]};
                *(ushort4v*)&PBo[b0]        = hv;
                *(ushort4v*)&PBo[b0 + 2048] = mv;
            } else {
#pragma unroll
                for (int j = 0; j < 4; ++j) {
                    const int r = rb0 + j;
                    if (r < M) {
                        outF[(size_t)r * D + c] = vv[j];
                        if (PAout) {
                            ushort h, m;
                            split2(vv[j], h, m);
                            const size_t a0 = pa_addr(r + ro, c, 0);
                            PAout[a0] = h; PAout[a0 + 4096] = m;
                        }
                    }
                }
            }
        }
    }
}

// ================= fp32 fallback (round-1, known-good) =================
__global__ void transpose_k(const float* __restrict__ A, float* __restrict__ T) {
    __shared__ float tile[32][33];
    const int bx = blockIdx.x * 32, by = blockIdx.y * 32;
    const int tx = threadIdx.x, ty = threadIdx.y;
#pragma unroll
    for (int i = 0; i < 32; i += 8)
        tile[ty + i][tx] = A[(size_t)(by + ty + i) * D + bx + tx];
    __syncthreads();
#pragma unroll
    for (int i = 0; i < 32; i += 8)
        T[(size_t)(bx + ty + i) * D + by + tx] = tile[tx][ty + i];
}

__global__ __launch_bounds__(256) void gemm_rows(const float* __restrict__ X,
                                                 const float* __restrict__ W,
                                                 float* __restrict__ C, int M) {
    __shared__ float As[16][34];
    __shared__ float Bs[16][68];
    const int n0 = blockIdx.x * 64;
    const int m0 = blockIdx.y * 32;
    const int tid = threadIdx.x;
    const int ty = tid >> 4, tx = tid & 15;
    const int rs = tid >> 3;
    const int ks = (tid & 7) * 2;
    const int rclamp = min(m0 + rs, M - 1);
    const int kb = tid >> 4;
    const int nb = (tid & 15) * 4;
    float acc[2][4] = {{0.f, 0.f, 0.f, 0.f}, {0.f, 0.f, 0.f, 0.f}};
    for (int k0 = 0; k0 < D; k0 += 16) {
        float2 xa = *reinterpret_cast<const float2*>(&X[(size_t)rclamp * D + k0 + ks]);
        float4 wb = *reinterpret_cast<const float4*>(&W[(size_t)(k0 + kb) * D + n0 + nb]);
        As[ks][rs] = xa.x;
        As[ks + 1][rs] = xa.y;
        *reinterpret_cast<float4*>(&Bs[kb][nb]) = wb;
        __syncthreads();
#pragma unroll
        for (int kk = 0; kk < 16; ++kk) {
            float2 a = *reinterpret_cast<const float2*>(&As[kk][ty * 2]);
            float4 b = *reinterpret_cast<const float4*>(&Bs[kk][tx * 4]);
            acc[0][0] += a.x * b.x; acc[0][1] += a.x * b.y;
            acc[0][2] += a.x * b.z; acc[0][3] += a.x * b.w;
            acc[1][0] += a.y * b.x; acc[1][1] += a.y * b.y;
            acc[1][2] += a.y * b.z; acc[1][3] += a.y * b.w;
        }
        __syncthreads();
    }
#pragma unroll
    for (int i = 0; i < 2; ++i) {
        const int m = m0 + ty * 2 + i;
        if (m < M) {
            float4 v = make_float4(acc[i][0], acc[i][1], acc[i][2], acc[i][3]);
            *reinterpret_cast<float4*>(&C[(size_t)m * D + n0 + tx * 4]) = v;
        }
    }
}

__global__ __launch_bounds__(256, 2) void gemm_big(const float* __restrict__ X,
                                                   const float* __restrict__ W,
                                                   float* __restrict__ C) {
    __shared__ float As[16][132];
    __shared__ float Bs[16][68];
    const int n0 = blockIdx.x * 64;
    const int m0 = blockIdx.y * 128;
    const int tid = threadIdx.x;
    const int ty = tid >> 4, tx = tid & 15;
    const int ra = tid >> 2;
    const int ka = (tid & 3) * 4;
    const int kb = tid >> 4;
    const int nb = (tid & 15) * 4;
    float acc[8][4];
#pragma unroll
    for (int i = 0; i < 8; ++i) { acc[i][0] = 0.f; acc[i][1] = 0.f; acc[i][2] = 0.f; acc[i][3] = 0.f; }
    for (int k0 = 0; k0 < D; k0 += 16) {
        float4 a0 = *reinterpret_cast<const float4*>(&X[(size_t)(m0 + ra) * D + k0 + ka]);
        float4 a1 = *reinterpret_cast<const float4*>(&X[(size_t)(m0 + ra + 64) * D + k0 + ka]);
        float4 wb = *reinterpret_cast<const float4*>(&W[(size_t)(k0 + kb) * D + n0 + nb]);
        As[ka][ra] = a0.x; As[ka + 1][ra] = a0.y; As[ka + 2][ra] = a0.z; As[ka + 3][ra] = a0.w;
        As[ka][ra + 64] = a1.x; As[ka + 1][ra + 64] = a1.y;
        As[ka + 2][ra + 64] = a1.z; As[ka + 3][ra + 64] = a1.w;
        *reinterpret_cast<float4*>(&Bs[kb][nb]) = wb;
        __syncthreads();
#pragma unroll
        for (int kk = 0; kk < 16; ++kk) {
            float4 a04 = *reinterpret_cast<const float4*>(&As[kk][ty * 8]);
            float4 a14 = *reinterpret_cast<const float4*>(&As[kk][ty * 8 + 4]);
            float4 b4  = *reinterpret_cast<const float4*>(&Bs[kk][tx * 4]);
            const float av[8] = {a04.x, a04.y, a04.z, a04.w, a14.x, a14.y, a14.z, a14.w};
            const float bv[4] = {b4.x, b4.y, b4.z, b4.w};
#pragma unroll
            for (int i = 0; i < 8; ++i)
#pragma unroll
                for (int j = 0; j < 4; ++j)
                    acc[i][j] += av[i] * bv[j];
        }
        __syncthreads();
    }
#pragma unroll
    for (int i = 0; i < 8; ++i) {
        float4 v = make_float4(acc[i][0], acc[i][1], acc[i][2], acc[i][3]);
        *reinterpret_cast<float4*>(&C[(size_t)(m0 + ty * 8 + i) * D + n0 + tx * 4]) = v;
    }
}

__global__ void matvec_rowdot(const float* __restrict__ A, const float* __restrict__ y,
                              float* __restrict__ out) {
    const int wave = threadIdx.x >> 6, lane = threadIdx.x & 63;
    const int row = blockIdx.x * 4 + wave;
    const float* ar = A + (size_t)row * D;
    float s = 0.f;
#pragma unroll 8
    for (int k = lane; k < D; k += 64) s += ar[k] * y[k];
#pragma unroll
    for (int off = 32; off; off >>= 1) s += __shfl_down(s, off);
    if (lane == 0) out[row] = s;
}

// ================= host =================
extern "C" void kernel_launch(void* const* d_in, const int* in_sizes, int n_in,
                              void* d_out, int out_size, void* d_ws, size_t ws_size,
                              hipStream_t stream) {
    const float* A = (const float*)d_in[0];
    const float* y_init = (const float*)d_in[1];
    float* out = (float*)d_out;

    const size_t packFull = (size_t)16 * 64 * 16384;   // 16 MiB per packed matrix
    const size_t need = 5 * packFull;                  // 80 MiB

    if (ws_size >= need) {
        char* c = (char*)d_ws;
        ushort* PT[2]; ushort* PN[2]; ushort* rg[2];
        PT[0] = (ushort*)c; c += packFull;
        PT[1] = (ushort*)c; c += packFull;
        PN[0] = (ushort*)c; c += packFull;
        PN[1] = (ushort*)c; c += packFull;
        rg[0] = (ushort*)c; c += packFull;
        rg[1] = PN[0];        // last read by squaring i=10; first write chain j=1

        prep_pack<<<dim3(32, 32), 256, 0, stream>>>(A, PN[0], PT[0]);

        // seed: rows[0] = y1 * T  (fp32 matvec over PB-packed T)
        seed_mv<<<32, 256, 0, stream>>>(y_init, PT[0], out, rg[0]);

        // fused squaring + doubling: i = 0..10
        int cur = 0;
        for (int i = 0; i < 11; ++i) {
            const int m = 1 << i;
            const int nd = (m + 127) / 128;
            gemm3<<<dim3(32, 16 + nd), 512, 0, stream>>>(
                PN[cur], rg[0], PT[cur],
                out + (size_t)m * D, rg[0], m,
                PN[cur ^ 1], PT[cur ^ 1],
                m, (i < 10) ? 1 : 0);
            cur ^= 1;
        }
        // cur == 1: PT[1] = T^2048

        // chain: rows[j*2048..(j+1)*2048) = rows[(j-1)*2048..) * T^2048
        for (int j = 1; j < STEPS / KB2; ++j) {
            gemm3<<<dim3(32, 16), 512, 0, stream>>>(
                rg[(j - 1) & 1], nullptr, PT[cur],
                out + (size_t)j * KB2 * D,
                (j < STEPS / KB2 - 1) ? rg[j & 1] : nullptr, 0,
                nullptr, nullptr, 2048, 0);
        }
    } else if (ws_size >= 2 * (size_t)D * D * sizeof(float)) {
        // fp32 fallback (round-1 path, known-good)
        float* Pa = (float*)d_ws;
        float* Pb = Pa + (size_t)D * D;
        transpose_k<<<dim3(D / 32, D / 32), dim3(32, 8), 0, stream>>>(A, Pa);
        gemm_rows<<<dim3(D / 64, 1), 256, 0, stream>>>(y_init, Pa, out, 1);
        float* cur = Pa;
        float* nxt = Pb;
        for (int m = 1; m < 256; m <<= 1) {
            gemm_rows<<<dim3(D / 64, (m + 31) / 32), 256, 0, stream>>>(
                out, cur, out + (size_t)m * D, m);
            gemm_big<<<dim3(D / 64, D / 128), 256, 0, stream>>>(cur, cur, nxt);
            float* t = cur; cur = nxt; nxt = t;
        }
        for (int j = 1; j < STEPS / 256; ++j) {
            gemm_rows<<<dim3(D / 64, 256 / 32), 256, 0, stream>>>(
                out + (size_t)(j - 1) * 256 * D, cur, out + (size_t)j * 256 * D, 256);
        }
    } else {
        matvec_rowdot<<<D / 4, 256, 0, stream>>>(A, y_init, out);
        for (int t = 1; t < STEPS; ++t)
            matvec_rowdot<<<D / 4, 256, 0, stream>>>(A, out + (size_t)(t - 1) * D,
                                                     out + (size_t)t * D);
    }
}